// Round 3
// baseline (2541.180 us; speedup 1.0000x reference)
//
#include <hip/hip_runtime.h>

// Monarch matrix: out = P(R_bdmm(P(L_bdmm(P(x))))) + bias, S=128, n=16384.
// Folded form (c = contiguous feature index of the input operand):
//   stage A: Y[t][p][q]      = sum_k L[p][q][k] * x[t][k*128+p]   (c=p, s=k)
//   stage B: out[t][i*128+j] = sum_m R[j][i][m] * Y[t][m*128+j]   (c=j, s=m, q=i)
// Both stages are the same kernel: lanes carry c (coalesced input reads),
// weights relaid to W[qc][s][c][q] and LDS-staged in double-buffered chunks,
// input re-read x8 across q-chunks (L3), weights L2-pinned per XCD (qc=bx&7).

#define NFEAT 16384
#define SDIM  128

// Relaid weights: W[qc][s][c][q] = src[c][qc*16+q][s]   (8 MB each)
__device__ float g_WA[8 * 128 * 128 * 16];
__device__ float g_WB[8 * 128 * 128 * 16];

__global__ __launch_bounds__(256) void relay_kernel(
    const float* __restrict__ src, float* __restrict__ dst) {
  __shared__ float t[16 * 132];
  const int tid = threadIdx.x;
  const int bx  = blockIdx.x;       // 1024 blocks: c = bx>>3, qc = bx&7
  const int c   = bx >> 3;
  const int qc  = bx & 7;
  // read 16 q-rows x 128 s (coalesced) into LDS [q][s pad132]
#pragma unroll
  for (int r = 0; r < 8; ++r) {
    const int f = r * 256 + tid;
    const int q = f >> 7, s = f & 127;
    t[q * 132 + s] = src[c * 16384 + (qc * 16 + q) * 128 + s];
  }
  __syncthreads();
  // write dst[(qc*128+s)*2048 + c*16 + q] : 64B runs over q
#pragma unroll
  for (int r = 0; r < 2; ++r) {
    const int slot = r * 256 + tid;
    const int q4 = slot & 3, s = slot >> 2;
    float4 v;
    v.x = t[(q4 * 4 + 0) * 132 + s];
    v.y = t[(q4 * 4 + 1) * 132 + s];
    v.z = t[(q4 * 4 + 2) * 132 + s];
    v.w = t[(q4 * 4 + 3) * 132 + s];
    *(float4*)&dst[(size_t)(qc * 128 + s) * 2048 + c * 16 + q4 * 4] = v;
  }
}

// Main stage kernel.  Block: 256 thr; c = tid&127, th = tid>>7.
// Tile: 16 t (thread: 8, t = t0 + th*8 + u), full c=128, Q=16 (q0 = qc*16).
// s-chunks of 2 (16 KB LDS), 64 iters, dbuf + 1-iter-ahead reg prefetch.
// MODE 0 = stage A (epilogue LDS-transpose -> Y[t][c][q]);
// MODE 1 = stage B (direct coalesced stores + bias).
#define STAGE_BODY(I, XC, XN, WC, WN)                                         \
  {                                                                           \
    const int b1 = ((I) + 1) & 1;                                             \
    if ((I) < 63) {                  /* 1. ds_write chunk I+1 (regs->LDS) */  \
      _Pragma("unroll") for (int r = 0; r < 4; ++r)                           \
          *(float4*)&lds[b1 * 4096 + (r * 256 + tid) * 4] = WN[r];            \
    }                                                                         \
    if ((I) + 2 < 64) {              /* 2. load w(I+2) -> regs */             \
      _Pragma("unroll") for (int r = 0; r < 4; ++r)                           \
          WC[r] = *(const float4*)(wbase + ((size_t)((I) + 2)) * 4096 +       \
                                   (r * 256 + tid) * 4);                      \
    }                                                                         \
    if ((I) + 1 < 64) {              /* 3. load x(I+1) -> XN (XN is dead) */  \
      _Pragma("unroll") for (int ss = 0; ss < 2; ++ss)                        \
          _Pragma("unroll") for (int u = 0; u < 8; ++u)                       \
              XN[ss * 8 + u] =                                                \
          xbase[(size_t)u * NFEAT + (((I) + 1) * 2 + ss) * 128];              \
    }                                                                         \
    /* 4. compute chunk I from buf[I&1] with XC */                            \
    _Pragma("unroll") for (int ss = 0; ss < 2; ++ss) {                        \
      const float* wq = &lds[((I)&1) * 4096 + ss * 2048 + c * 16];            \
      const float4 w0 = *(const float4*)(wq + 0);                             \
      const float4 w1 = *(const float4*)(wq + 4);                             \
      const float4 w2 = *(const float4*)(wq + 8);                             \
      const float4 w3 = *(const float4*)(wq + 12);                            \
      const float wv[16] = {w0.x, w0.y, w0.z, w0.w, w1.x, w1.y, w1.z, w1.w,   \
                            w2.x, w2.y, w2.z, w2.w, w3.x, w3.y, w3.z, w3.w};  \
      _Pragma("unroll") for (int u = 0; u < 8; ++u)                           \
          _Pragma("unroll") for (int q = 0; q < 16; ++q)                      \
              acc[u][q] = fmaf(XC[ss * 8 + u], wv[q], acc[u][q]);             \
    }                                                                         \
    __syncthreads();                                                          \
  }

template <int MODE>
__global__ __launch_bounds__(256, 2) void stage_kernel(
    const float* __restrict__ X, const float* __restrict__ W,
    const float* __restrict__ bias, float* __restrict__ OUT) {
  __shared__ float lds[10240];  // 40 KB: w-dbuf (2x4096 fl) / epilogue scratch

  const int tid = threadIdx.x;
  const int c   = tid & 127;
  const int th  = tid >> 7;
  const int bx  = blockIdx.x;
  const int qc  = bx & 7;       // == XCD (RR dispatch): 1 MB w-slice L2-pinned
  const int tt  = bx >> 3;
  const int t0  = tt << 4;
  const int q0  = qc << 4;

  const float* xbase = X + (size_t)(t0 + th * 8) * NFEAT + c;
  const float* wbase = W + (size_t)qc * (128 * 2048);

  float acc[8][16];
#pragma unroll
  for (int u = 0; u < 8; ++u)
#pragma unroll
    for (int q = 0; q < 16; ++q) acc[u][q] = 0.f;

  float  xr0[16], xr1[16];
  float4 wr0[4], wr1[4];

  // prologue: w(0)->wr0 -> LDS buf0; w(1)->wr1; x(0)->xr0; barrier drains all.
#pragma unroll
  for (int r = 0; r < 4; ++r)
    wr0[r] = *(const float4*)(wbase + (r * 256 + tid) * 4);
#pragma unroll
  for (int ss = 0; ss < 2; ++ss)
#pragma unroll
    for (int u = 0; u < 8; ++u)
      xr0[ss * 8 + u] = xbase[(size_t)u * NFEAT + ss * 128];
#pragma unroll
  for (int r = 0; r < 4; ++r)
    *(float4*)&lds[(r * 256 + tid) * 4] = wr0[r];
#pragma unroll
  for (int r = 0; r < 4; ++r)
    wr1[r] = *(const float4*)(wbase + 4096 + (r * 256 + tid) * 4);
  __syncthreads();

  for (int i = 0; i < 64; i += 2) {
    STAGE_BODY(i,     xr0, xr1, wr0, wr1)
    STAGE_BODY(i + 1, xr1, xr0, wr1, wr0)
  }

  if constexpr (MODE == 0) {
    // epilogue A: LDS-transpose so Y[t][c*128 + q0+q] is written in 64B runs.
    // round r handles t-quad t0+4r..+3 (writers: th == r>>1, u = (r&1)*4+uu).
    for (int r = 0; r < 4; ++r) {
      if (th == (r >> 1)) {
        const int u0 = (r & 1) * 4;
#pragma unroll
        for (int uu = 0; uu < 4; ++uu)
#pragma unroll
          for (int q4 = 0; q4 < 4; ++q4) {
            float4 v;
            v.x = acc[u0 + uu][q4 * 4 + 0];
            v.y = acc[u0 + uu][q4 * 4 + 1];
            v.z = acc[u0 + uu][q4 * 4 + 2];
            v.w = acc[u0 + uu][q4 * 4 + 3];
            *(float4*)&lds[(uu * 128 + c) * 20 + q4 * 4] = v;
          }
      }
      __syncthreads();
#pragma unroll
      for (int r2 = 0; r2 < 8; ++r2) {
        const int slot = r2 * 256 + tid;
        const int q4 = slot & 3, cc = (slot >> 2) & 127, uu = slot >> 9;
        const float4 v = *(const float4*)&lds[(uu * 128 + cc) * 20 + q4 * 4];
        *(float4*)&OUT[(size_t)(t0 + r * 4 + uu) * NFEAT + cc * 128 + q0 +
                       q4 * 4] = v;
      }
      __syncthreads();
    }
  } else {
    // epilogue B: lanes are j (contiguous) -> direct coalesced stores + bias.
    float bv[16];
#pragma unroll
    for (int q = 0; q < 16; ++q) bv[q] = bias[(q0 + q) * 128 + c];
#pragma unroll
    for (int u = 0; u < 8; ++u)
#pragma unroll
      for (int q = 0; q < 16; ++q)
        OUT[(size_t)(t0 + th * 8 + u) * NFEAT + (q0 + q) * 128 + c] =
            acc[u][q] + bv[q];
  }
}

extern "C" void kernel_launch(void* const* d_in, const int* in_sizes, int n_in,
                              void* d_out, int out_size, void* d_ws, size_t ws_size,
                              hipStream_t stream) {
  const float* x    = (const float*)d_in[0];
  const float* L    = (const float*)d_in[1];
  const float* R    = (const float*)d_in[2];
  const float* bias = (const float*)d_in[3];
  float* out = (float*)d_out;

  const int rows = in_sizes[0] / NFEAT;  // 4096
  float* Y = (float*)d_ws;               // 256 MB (confirmed >= y_bytes in r2)

  float* wa;
  float* wb;
  hipGetSymbolAddress((void**)&wa, HIP_SYMBOL(g_WA));
  hipGetSymbolAddress((void**)&wb, HIP_SYMBOL(g_WB));

  relay_kernel<<<1024, 256, 0, stream>>>(L, wa);
  relay_kernel<<<1024, 256, 0, stream>>>(R, wb);

  const int nblk = (rows / 16) * 8;      // 2048
  stage_kernel<0><<<nblk, 256, 0, stream>>>(x, wa, nullptr, Y);
  stage_kernel<1><<<nblk, 256, 0, stream>>>(Y, wb, bias, out);
}